// Round 10
// baseline (145.358 us; speedup 1.0000x reference)
//
#include <hip/hip_runtime.h>
#include <math.h>

// Problem constants
#define N_  64
#define TC_ 256
#define K_  32
#define TK_ 64
#define D_  256
#define D4_ 64            // float4 per embedding row
#define TF_ 320           // TK + TC
#define V_  32000

// ws layout (float offsets):
//   ctxTg [D][N]  f32  @ 0       (zeroed; transposed ctx raw sums)
//   clen  [N]     int  @ 16384   (zeroed)
//   score [N][K]  f32  @ 16448   (fallback path only)
//   P     [V][N]  f32  @ 18496   (P-table path only)
#define WS_CTXT   0
#define WS_CLEN   (D_ * N_)
#define WS_SCORE  (WS_CLEN + N_)
#define WS_P      (WS_SCORE + N_ * K_)
#define WS_FLOATS_P ((size_t)WS_P + (size_t)V_ * N_)   // 2,066,496 f = 8.27 MB

// ---------------------------------------------------------------------------
// k1: context gather (float4). Writes ctx part of full_enc/full_mask;
//     atomically accumulates raw ctx sums into transposed ctxTg[d][n] + clen.
// grid = N*8 (32 tokens per block), block = 256 (4 waves)
// ---------------------------------------------------------------------------
__global__ __launch_bounds__(256) void k1_ctx(
        const int* __restrict__ src, const float4* __restrict__ embed4,
        float4* __restrict__ out_enc4, float* __restrict__ out_mask,
        float* __restrict__ ctxTg, int* __restrict__ clen) {
    const int n = blockIdx.x >> 3;
    const int c = blockIdx.x & 7;
    const int tid = threadIdx.x, w = tid >> 6, l = tid & 63;

    __shared__ int    toks[32];
    __shared__ float4 part[4][64];

    if (tid < 32) {
        const int tok = src[n * TC_ + c * 32 + tid];
        toks[tid] = tok;
        out_mask[n * TF_ + TK_ + c * 32 + tid] = tok ? 1.f : 0.f;
    }
    __syncthreads();

    float4 acc = {0.f, 0.f, 0.f, 0.f};
    #pragma unroll
    for (int i = 0; i < 8; ++i) {
        const int t = w * 8 + i;                  // wave w owns tokens [8w,8w+8)
        const int tok = toks[t];                  // wave-uniform -> scalar branch
        float4 v = {0.f, 0.f, 0.f, 0.f};
        if (tok) v = embed4[(size_t)tok * D4_ + l];
        out_enc4[((size_t)n * TF_ + TK_ + c * 32 + t) * D4_ + l] = v;
        acc.x += v.x; acc.y += v.y; acc.z += v.z; acc.w += v.w;
    }
    part[w][l] = acc;
    __syncthreads();

    if (w == 0) {
        float4 a = part[0][l], b = part[1][l], p2 = part[2][l], p3 = part[3][l];
        a.x += b.x + p2.x + p3.x;  a.y += b.y + p2.y + p3.y;
        a.z += b.z + p2.z + p3.z;  a.w += b.w + p2.w + p3.w;
        atomicAdd(&ctxTg[(4 * l + 0) * N_ + n], a.x);   // lane l owns dims 4l..4l+3
        atomicAdd(&ctxTg[(4 * l + 1) * N_ + n], a.y);
        atomicAdd(&ctxTg[(4 * l + 2) * N_ + n], a.z);
        atomicAdd(&ctxTg[(4 * l + 3) * N_ + n], a.w);
        const unsigned long long ball = __ballot(l < 32 && toks[l] != 0);
        if (l == 0) atomicAdd(&clen[n], __popcll(ball));
    }
}

// ---------------------------------------------------------------------------
// k2: P[v][n] = embed[v] . ctx_sum[n]   (f32 VALU GEMM, 1.05 GFLOP)
// grid = 1000 blocks x 256 thr; each wave: 8 rows, lane = n.
// ctx chunk (64 dims) in VGPRs (coalesced from ctxTg); embed row loads are
// wave-uniform (readfirstlane) -> scalar-cache broadcast.
// ---------------------------------------------------------------------------
__global__ __launch_bounds__(256) void k2_gemm(
        const float* __restrict__ embed, const float* __restrict__ ctxTg,
        float* __restrict__ P) {
    const int tid = threadIdx.x, w = tid >> 6, l = tid & 63;
    const int v0 = blockIdx.x * 32 + w * 8;       // 8 rows per wave
    float acc[8] = {0.f, 0.f, 0.f, 0.f, 0.f, 0.f, 0.f, 0.f};
    #pragma unroll
    for (int dc = 0; dc < 4; ++dc) {              // 4 chunks of 64 dims
        float ctxv[64];
        #pragma unroll
        for (int dd = 0; dd < 64; ++dd)
            ctxv[dd] = ctxTg[(size_t)(dc * 64 + dd) * N_ + l];  // coalesced
        #pragma unroll
        for (int r = 0; r < 8; ++r) {
            const int vr = __builtin_amdgcn_readfirstlane(v0 + r);
            const float* row = embed + (size_t)vr * D_ + dc * 64;
            #pragma unroll
            for (int dd = 0; dd < 64; ++dd)
                acc[r] = fmaf(row[dd], ctxv[dd], acc[r]);       // uniform x lane
        }
    }
    #pragma unroll
    for (int r = 0; r < 8; ++r)
        P[(size_t)(v0 + r) * N_ + l] = acc[r];    // coalesced 256B
}

// ---------------------------------------------------------------------------
// k3: scores from P lookups (4B/token), argmax (first-max = jnp.argmax) or
//     cs_ids, selected-span gather, ck_attn write. grid = N blocks.
// ---------------------------------------------------------------------------
__global__ __launch_bounds__(256) void k3_sel(
        const int* __restrict__ know, const int* __restrict__ ckm,
        const int* __restrict__ cs_ids, const int* __restrict__ use_flag,
        const float* __restrict__ embed, const float* __restrict__ P,
        const int* __restrict__ clen,
        float* __restrict__ out_enc, float* __restrict__ out_mask,
        float* __restrict__ out_attn) {
    const int n = blockIdx.x;
    const int tid = threadIdx.x, w = tid >> 6, l = tid & 63;
    const float4* embed4   = (const float4*)embed;
    float4*       out_enc4 = (float4*)out_enc;

    __shared__ float sc_attn[K_], sc_arg[K_];
    __shared__ int   toks[TK_];
    __shared__ int   cs_sh;

    const float lc_f = (float)max(clen[n], 1);
    #pragma unroll
    for (int j = 0; j < 8; ++j) {                 // wave w -> k = 8w+j
        const int k = w * 8 + j;
        const int tok = know[((size_t)n * K_ + k) * TK_ + l];
        float p = (tok != 0) ? P[(size_t)tok * N_ + n] : 0.f;
        #pragma unroll
        for (int o = 32; o > 0; o >>= 1) p += __shfl_down(p, o, 64);
        const unsigned long long ball = __ballot(tok != 0);
        if (l == 0) {
            const int ck = ckm[n * K_ + k];
            int lk = ck ? __popcll(ball) : 0;  if (lk < 1) lk = 1;
            const float score =
                p / (sqrtf((float)D_ * lc_f) * sqrtf((float)(D_ * lk)));
            sc_attn[k] = ck ? score : 0.f;
            sc_arg[k]  = ck ? score : -INFINITY;
        }
    }
    __syncthreads();
    if (tid == 0) {
        int cs;
        if (use_flag[0]) {
            cs = cs_ids[n];
        } else {
            float best = -INFINITY; cs = 0;
            #pragma unroll
            for (int jj = 0; jj < K_; ++jj) {
                const float s = sc_arg[jj];
                if (s > best) { best = s; cs = jj; }   // first-max tie-break
            }
        }
        cs_sh = cs;
    }
    if (tid < K_) out_attn[n * K_ + tid] = sc_attn[tid];
    __syncthreads();
    const int cs = cs_sh;
    const int ck = ckm[n * K_ + cs];
    if (tid < TK_) {
        const int tok = know[((size_t)n * K_ + cs) * TK_ + tid];
        toks[tid] = tok;
        out_mask[n * TF_ + tid] = (ck && tok) ? 1.f : 0.f;
    }
    __syncthreads();
    #pragma unroll
    for (int i = 0; i < 16; ++i) {
        const int t = w * 16 + i;
        const int tok = toks[t];                  // wave-uniform per iter
        float4 v = {0.f, 0.f, 0.f, 0.f};
        if (ck && tok) v = embed4[(size_t)tok * D4_ + l];
        out_enc4[((size_t)n * TF_ + t) * D4_ + l] = v;
    }
}

// ---------------------------------------------------------------------------
// Fallback path (ws too small for P): per-(n,k) row pooling (R2-proven shape).
// ---------------------------------------------------------------------------
__global__ __launch_bounds__(256) void f2_kb(
        const int* __restrict__ know, const int* __restrict__ ckm,
        const float4* __restrict__ embed4, const float* __restrict__ ctxTg,
        const int* __restrict__ clen,
        float* __restrict__ out_attn, float* __restrict__ ws_score) {
    const int n = blockIdx.x >> 5;
    const int k = blockIdx.x & (K_ - 1);
    const int tid = threadIdx.x, w = tid >> 6, l = tid & 63;

    __shared__ int   toks[TK_];
    __shared__ float redp[4];
    __shared__ int   lk_sh;

    if (tid < TK_) toks[tid] = know[((size_t)n * K_ + k) * TK_ + tid];
    __syncthreads();
    const int ck = ckm[n * K_ + k];

    float4 ctx;
    ctx.x = ctxTg[(4 * l + 0) * N_ + n];
    ctx.y = ctxTg[(4 * l + 1) * N_ + n];
    ctx.z = ctxTg[(4 * l + 2) * N_ + n];
    ctx.w = ctxTg[(4 * l + 3) * N_ + n];

    float4 acc = {0.f, 0.f, 0.f, 0.f};
    if (ck) {
        #pragma unroll
        for (int i = 0; i < 16; ++i) {
            const int tok = toks[w * 16 + i];
            if (tok) {
                const float4 v = embed4[(size_t)tok * D4_ + l];
                acc.x += v.x; acc.y += v.y; acc.z += v.z; acc.w += v.w;
            }
        }
    }
    float p = acc.x * ctx.x + acc.y * ctx.y + acc.z * ctx.z + acc.w * ctx.w;
    #pragma unroll
    for (int o = 32; o > 0; o >>= 1) p += __shfl_down(p, o, 64);
    if (l == 0) redp[w] = p;
    if (w == 0) {
        const unsigned long long ball = __ballot(toks[l] != 0);
        if (l == 0) lk_sh = __popcll(ball);
    }
    __syncthreads();
    if (tid == 0) {
        const float dot = redp[0] + redp[1] + redp[2] + redp[3];
        const int lc = max(clen[n], 1);
        int lk = ck ? lk_sh : 0;  if (lk < 1) lk = 1;
        const float score =
            dot / (sqrtf((float)(D_ * lc)) * sqrtf((float)(D_ * lk)));
        out_attn[n * K_ + k] = ck ? score : 0.f;
        ws_score[n * K_ + k] = ck ? score : -INFINITY;
    }
}

__global__ __launch_bounds__(256) void f3_sel(
        const int* __restrict__ know, const int* __restrict__ ckm,
        const int* __restrict__ cs_ids, const int* __restrict__ use_flag,
        const float4* __restrict__ embed4, const float* __restrict__ ws_score,
        float4* __restrict__ out_enc4, float* __restrict__ out_mask) {
    const int n = blockIdx.x >> 2;
    const int c = blockIdx.x & 3;
    const int tid = threadIdx.x, w = tid >> 6, l = tid & 63;

    int cs = 0;
    if (use_flag[0]) {
        cs = cs_ids[n];
    } else {
        float best = -INFINITY;
        #pragma unroll
        for (int j = 0; j < K_; ++j) {
            const float s = ws_score[n * K_ + j];
            if (s > best) { best = s; cs = j; }
        }
    }
    const int ck = ckm[n * K_ + cs];

    __shared__ int toks[16];
    if (tid < 16) {
        const int tok = know[((size_t)n * K_ + cs) * TK_ + c * 16 + tid];
        toks[tid] = tok;
        out_mask[n * TF_ + c * 16 + tid] = (ck && tok) ? 1.f : 0.f;
    }
    __syncthreads();
    #pragma unroll
    for (int i = 0; i < 4; ++i) {
        const int t = w * 4 + i;
        const int tok = toks[t];
        float4 v = {0.f, 0.f, 0.f, 0.f};
        if (ck && tok) v = embed4[(size_t)tok * D4_ + l];
        out_enc4[((size_t)n * TF_ + c * 16 + t) * D4_ + l] = v;
    }
}

// ---------------------------------------------------------------------------
extern "C" void kernel_launch(void* const* d_in, const int* in_sizes, int n_in,
                              void* d_out, int out_size, void* d_ws, size_t ws_size,
                              hipStream_t stream) {
    const int*   src      = (const int*)d_in[0];    // [N,TC]
    const int*   know     = (const int*)d_in[1];    // [N,K,TK]
    const int*   ckm      = (const int*)d_in[2];    // [N,K]
    const int*   cs_ids   = (const int*)d_in[3];    // [N]
    const int*   use_flag = (const int*)d_in[4];    // scalar
    const float* embed    = (const float*)d_in[5];  // [V,D]

    float* out      = (float*)d_out;
    float* out_mask = out + (size_t)N_ * TF_ * D_;
    float* out_attn = out_mask + N_ * TF_;

    float* ws    = (float*)d_ws;
    float* ctxTg = ws + WS_CTXT;
    int*   clen  = (int*)(ws + WS_CLEN);
    float* wsc   = ws + WS_SCORE;
    float* P     = ws + WS_P;

    // zero the atomic accumulators (ctxTg + clen): 65,792 bytes
    hipMemsetAsync(d_ws, 0, (size_t)(WS_CLEN + N_) * sizeof(float), stream);

    hipLaunchKernelGGL(k1_ctx, dim3(N_ * 8), dim3(256), 0, stream,
                       src, (const float4*)embed, (float4*)out, out_mask,
                       ctxTg, clen);

    if (ws_size >= WS_FLOATS_P * sizeof(float)) {
        // P-table path: 4B/token scoring
        hipLaunchKernelGGL(k2_gemm, dim3(V_ / 32), dim3(256), 0, stream,
                           embed, ctxTg, P);
        hipLaunchKernelGGL(k3_sel, dim3(N_), dim3(256), 0, stream,
                           know, ckm, cs_ids, use_flag, embed, P, clen,
                           out, out_mask, out_attn);
    } else {
        // fallback: per-(n,k) pooling (proven structure)
        hipLaunchKernelGGL(f2_kb, dim3(N_ * K_), dim3(256), 0, stream,
                           know, ckm, (const float4*)embed, ctxTg, clen,
                           out_attn, wsc);
        hipLaunchKernelGGL(f3_sel, dim3(N_ * 4), dim3(256), 0, stream,
                           know, ckm, cs_ids, use_flag, (const float4*)embed,
                           wsc, (float4*)out, out_mask);
    }
}

// Round 11
// 139.230 us; speedup vs baseline: 1.0440x; 1.0440x over previous
//
#include <hip/hip_runtime.h>
#include <math.h>

// Problem constants
#define N_  64
#define TC_ 256
#define K_  32
#define TK_ 64
#define D_  256
#define D4_ 64            // float4 per embedding row
#define TF_ 320           // TK + TC
#define V_  32000

// ---------------------------------------------------------------------------
// Single-dispatch kernel. The problem is per-n independent:
//   blocks 0..63   : "know" block for n = blockIdx.x
//                    (a) recompute ctx raw sum + ctx_len from src (L2-hot rows)
//                    (b) pooled scores for all 32 k
//                    (c) argmax (first-max = jnp.argmax) or cs_ids
//                    (d) gather selected span -> out_enc[0:TK], out_mask[0:TK],
//                        out_attn
//   blocks 64..191 : "ctx" block for n = (b-64)>>1, half = (b-64)&1
//                    gather 128 ctx rows -> out_enc[TK:], out_mask[TK:]
// No ws, no atomics, no memset, no inter-block communication.
// block = 1024 threads (16 waves); lane l owns dims [4l, 4l+4) of a row.
// ---------------------------------------------------------------------------
__global__ __launch_bounds__(1024) void cke_all(
        const int* __restrict__ src, const int* __restrict__ know,
        const int* __restrict__ ckm, const int* __restrict__ cs_ids,
        const int* __restrict__ use_flag, const float* __restrict__ embed,
        float* __restrict__ out) {
    const int tid = threadIdx.x, w = tid >> 6, l = tid & 63;

    float* out_mask = out + (size_t)N_ * TF_ * D_;   // [N,TF]
    float* out_attn = out_mask + N_ * TF_;           // [N,K]
    const float4* embed4   = (const float4*)embed;
    float4*       out_enc4 = (float4*)out;           // [N,TF,D/4]

    // ---------------- ctx blocks: pure gather ----------------
    if (blockIdx.x >= N_) {
        const int b = blockIdx.x - N_;
        const int n = b >> 1, c = b & 1;             // tokens [c*128, c*128+128)
        __shared__ int toks[128];
        if (tid < 128) {
            const int tok = src[n * TC_ + c * 128 + tid];
            toks[tid] = tok;
            out_mask[n * TF_ + TK_ + c * 128 + tid] = tok ? 1.f : 0.f;
        }
        __syncthreads();
        #pragma unroll
        for (int i = 0; i < 8; ++i) {                // wave w: tokens [8w, 8w+8)
            const int t = w * 8 + i;
            const int tok = toks[t];                 // wave-uniform -> scalar branch
            float4 v = {0.f, 0.f, 0.f, 0.f};
            if (tok) v = embed4[(size_t)tok * D4_ + l];
            out_enc4[((size_t)n * TF_ + TK_ + c * 128 + t) * D4_ + l] = v;
        }
        return;
    }

    // ---------------- know block for n ----------------
    const int n = blockIdx.x;

    __shared__ int    ctoks[TC_];                    // 1 KB
    __shared__ int    ktoks[K_ * TK_];               // 8 KB
    __shared__ float4 part[16][64];                  // 16 KB
    __shared__ float4 ctx4[64];                      // 1 KB
    __shared__ int    wcnt[16];
    __shared__ float  sc_attn[K_], sc_arg[K_];
    __shared__ int    cs_sh, clen_sh;

    if (tid < TC_) ctoks[tid] = src[n * TC_ + tid];
    #pragma unroll
    for (int i = tid; i < K_ * TK_; i += 1024)
        ktoks[i] = know[(size_t)n * K_ * TK_ + i];
    __syncthreads();

    // Phase 1: ctx raw sum (recompute; rows are L2/L3-hot) + ctx_len
    {
        float4 acc = {0.f, 0.f, 0.f, 0.f};
        #pragma unroll
        for (int i = 0; i < 16; ++i) {               // wave w: tokens [16w,16w+16)
            const int tok = ctoks[w * 16 + i];       // uniform -> scalar branch
            if (tok) {
                const float4 v = embed4[(size_t)tok * D4_ + l];
                acc.x += v.x; acc.y += v.y; acc.z += v.z; acc.w += v.w;
            }
        }
        part[w][l] = acc;
        const unsigned long long ball = __ballot(l < 16 && ctoks[w * 16 + l] != 0);
        if (l == 0) wcnt[w] = __popcll(ball);
    }
    __syncthreads();
    if (tid < 64) {
        float4 s = {0.f, 0.f, 0.f, 0.f};
        #pragma unroll
        for (int wv = 0; wv < 16; ++wv) {
            const float4 v = part[wv][tid];
            s.x += v.x; s.y += v.y; s.z += v.z; s.w += v.w;
        }
        ctx4[tid] = s;
    }
    if (tid == 0) {
        int c = 0;
        #pragma unroll
        for (int i = 0; i < 16; ++i) c += wcnt[i];
        clen_sh = c;
    }
    __syncthreads();

    // Phase 2: pooled scores; wave w handles k = 2w, 2w+1
    {
        const float4 cx = ctx4[l];
        #pragma unroll
        for (int j = 0; j < 2; ++j) {
            const int kk = w * 2 + j;
            float4 acc = {0.f, 0.f, 0.f, 0.f};
            #pragma unroll 8
            for (int t = 0; t < TK_; ++t) {
                const int tok = ktoks[kk * TK_ + t]; // uniform -> scalar branch
                if (tok) {
                    const float4 v = embed4[(size_t)tok * D4_ + l];
                    acc.x += v.x; acc.y += v.y; acc.z += v.z; acc.w += v.w;
                }
            }
            float p = acc.x * cx.x + acc.y * cx.y + acc.z * cx.z + acc.w * cx.w;
            #pragma unroll
            for (int o = 32; o > 0; o >>= 1) p += __shfl_down(p, o, 64);
            const unsigned long long ball = __ballot(ktoks[kk * TK_ + l] != 0);
            if (l == 0) {
                const int ck = ckm[n * K_ + kk];
                int lk = ck ? __popcll(ball) : 0;  if (lk < 1) lk = 1;
                const int lc = max(clen_sh, 1);
                const float score =
                    p / (sqrtf((float)(D_ * lc)) * sqrtf((float)(D_ * lk)));
                sc_attn[kk] = ck ? score : 0.f;
                sc_arg[kk]  = ck ? score : -INFINITY;
            }
        }
    }
    __syncthreads();

    // Phase 3: select
    if (tid == 0) {
        int cs;
        if (use_flag[0]) {
            cs = cs_ids[n];
        } else {
            float best = -INFINITY; cs = 0;
            #pragma unroll
            for (int jj = 0; jj < K_; ++jj) {
                const float s = sc_arg[jj];
                if (s > best) { best = s; cs = jj; }  // first-max tie-break
            }
        }
        cs_sh = cs;
    }
    if (tid < K_) out_attn[n * K_ + tid] = sc_attn[tid];
    __syncthreads();

    // Phase 4: gather selected span -> slots [0, TK)
    const int cs = cs_sh;
    const int ck = ckm[n * K_ + cs];
    if (tid < TK_) {
        const int tok = ktoks[cs * TK_ + tid];
        out_mask[n * TF_ + tid] = (ck && tok) ? 1.f : 0.f;
    }
    #pragma unroll
    for (int i = 0; i < 4; ++i) {                    // wave w: rows [4w, 4w+4)
        const int t = w * 4 + i;
        const int tok = ktoks[cs * TK_ + t];         // uniform -> scalar branch
        float4 v = {0.f, 0.f, 0.f, 0.f};
        if (ck && tok) v = embed4[(size_t)tok * D4_ + l];
        out_enc4[((size_t)n * TF_ + t) * D4_ + l] = v;
    }
}

// ---------------------------------------------------------------------------
extern "C" void kernel_launch(void* const* d_in, const int* in_sizes, int n_in,
                              void* d_out, int out_size, void* d_ws, size_t ws_size,
                              hipStream_t stream) {
    const int*   src      = (const int*)d_in[0];    // [N,TC]
    const int*   know     = (const int*)d_in[1];    // [N,K,TK]
    const int*   ckm      = (const int*)d_in[2];    // [N,K]
    const int*   cs_ids   = (const int*)d_in[3];    // [N]
    const int*   use_flag = (const int*)d_in[4];    // scalar
    const float* embed    = (const float*)d_in[5];  // [V,D]

    hipLaunchKernelGGL(cke_all, dim3(N_ * 3), dim3(1024), 0, stream,
                       src, know, ckm, cs_ids, use_flag, embed, (float*)d_out);
}

// Round 12
// 114.783 us; speedup vs baseline: 1.2664x; 1.2130x over previous
//
#include <hip/hip_runtime.h>
#include <math.h>

// Problem constants
#define N_  64
#define TC_ 256
#define K_  32
#define TK_ 64
#define D_  256
#define D4_ 64            // float4 per embedding row
#define TF_ 320           // TK + TC
#define V_  32000

// ws layout (float offsets) — every slot written before read, no memset:
//   part   [1024][D]  f32  @ 0        per-(n,16-token-chunk) ctx partial sums
//   clen_p [1024]     int  @ 262144   per-chunk ctx token counts
//   score  [N][K]     f32  @ 263168   ck-masked scores (-inf pad) for argmax
#define WS_CLENP  262144
#define WS_SCORE  263168

// ---------------------------------------------------------------------------
// k1: ctx gather. grid = N*16 (16 tokens/block), block = 256 (4 waves).
// Writes ctx part of full_enc/full_mask + per-chunk partial sums/counts.
// 1024 blocks = 4 blocks/CU -> 16 waves/CU during the gather.
// ---------------------------------------------------------------------------
__global__ __launch_bounds__(256) void k1_ctx(
        const int* __restrict__ src, const float4* __restrict__ embed4,
        float4* __restrict__ out_enc4, float* __restrict__ out_mask,
        float4* __restrict__ ws_part4, int* __restrict__ clen_p) {
    const int b = blockIdx.x, n = b >> 4, c = b & 15;
    const int tid = threadIdx.x, w = tid >> 6, l = tid & 63;

    __shared__ int    toks[16];
    __shared__ float4 part[4][64];

    if (tid < 16) {
        const int tok = src[n * TC_ + c * 16 + tid];
        toks[tid] = tok;
        out_mask[n * TF_ + TK_ + c * 16 + tid] = tok ? 1.f : 0.f;
    }
    __syncthreads();

    float4 acc = {0.f, 0.f, 0.f, 0.f};
    #pragma unroll
    for (int i = 0; i < 4; ++i) {                 // wave w: tokens [4w, 4w+4)
        const int t = w * 4 + i;
        const int tok = toks[t];                  // wave-uniform -> scalar branch
        float4 v = {0.f, 0.f, 0.f, 0.f};
        if (tok) v = embed4[(size_t)tok * D4_ + l];
        out_enc4[((size_t)n * TF_ + TK_ + c * 16 + t) * D4_ + l] = v;
        acc.x += v.x; acc.y += v.y; acc.z += v.z; acc.w += v.w;
    }
    part[w][l] = acc;
    __syncthreads();

    if (w == 0) {
        float4 a = part[0][l], b1 = part[1][l], p2 = part[2][l], p3 = part[3][l];
        a.x += b1.x + p2.x + p3.x;  a.y += b1.y + p2.y + p3.y;
        a.z += b1.z + p2.z + p3.z;  a.w += b1.w + p2.w + p3.w;
        ws_part4[(size_t)b * D4_ + l] = a;
        const unsigned long long ball = __ballot(l < 16 && toks[l] != 0);
        if (l == 0) clen_p[b] = __popcll(ball);
    }
}

// ---------------------------------------------------------------------------
// k2: knowledge scoring. grid = N*K = 2048 (one block per (n,k)), block = 256.
// 2048 blocks = 8/CU x 4 waves = 32 waves/CU: full-machine latency hiding.
// ctx sum staged once into LDS (wave 0 sums the 16 chunk partials); clen
// reduced by wave 1. 4 waves x 16 rows pooled gather, dot, reduce, score.
// ---------------------------------------------------------------------------
__global__ __launch_bounds__(256) void k2_know(
        const int* __restrict__ know, const int* __restrict__ ckm,
        const float4* __restrict__ embed4,
        const float4* __restrict__ ws_part4, const int* __restrict__ clen_p,
        float* __restrict__ out_attn, float* __restrict__ ws_score) {
    const int b = blockIdx.x, n = b >> 5, k = b & (K_ - 1);
    const int tid = threadIdx.x, w = tid >> 6, l = tid & 63;

    __shared__ int    ktoks[TK_];
    __shared__ float4 ctx4[64];
    __shared__ float  redp[4];
    __shared__ int    lk_sh, lc_sh;

    if (tid < TK_) ktoks[tid] = know[((size_t)n * K_ + k) * TK_ + tid];
    if (w == 0) {                                 // stage ctx sum into LDS
        float4 s = {0.f, 0.f, 0.f, 0.f};
        #pragma unroll
        for (int c = 0; c < 16; ++c) {
            const float4 v = ws_part4[(size_t)(n * 16 + c) * D4_ + l];
            s.x += v.x; s.y += v.y; s.z += v.z; s.w += v.w;
        }
        ctx4[l] = s;
    } else if (w == 1) {                          // reduce ctx length
        int cl = (l < 16) ? clen_p[n * 16 + l] : 0;
        #pragma unroll
        for (int o = 32; o > 0; o >>= 1) cl += __shfl_down(cl, o, 64);
        if (l == 0) lc_sh = cl;
    }
    __syncthreads();

    float4 acc = {0.f, 0.f, 0.f, 0.f};
    #pragma unroll
    for (int i = 0; i < 16; ++i) {                // wave w: rows [16w, 16w+16)
        const int tok = ktoks[w * 16 + i];        // wave-uniform -> scalar branch
        if (tok) {
            const float4 v = embed4[(size_t)tok * D4_ + l];
            acc.x += v.x; acc.y += v.y; acc.z += v.z; acc.w += v.w;
        }
    }
    const float4 cx = ctx4[l];
    float p = acc.x * cx.x + acc.y * cx.y + acc.z * cx.z + acc.w * cx.w;
    #pragma unroll
    for (int o = 32; o > 0; o >>= 1) p += __shfl_down(p, o, 64);
    if (l == 0) redp[w] = p;
    if (w == 0) {
        const unsigned long long ball = __ballot(ktoks[l] != 0);
        if (l == 0) lk_sh = __popcll(ball);
    }
    __syncthreads();

    if (tid == 0) {
        const float dot = redp[0] + redp[1] + redp[2] + redp[3];
        const int ck = ckm[n * K_ + k];
        const int lc = max(lc_sh, 1);
        int lk = ck ? lk_sh : 0;  if (lk < 1) lk = 1;   // know_mask includes ck
        const float score =
            dot / (sqrtf((float)(D_ * lc)) * sqrtf((float)(D_ * lk)));
        out_attn[n * K_ + k] = ck ? score : 0.f;
        ws_score[n * K_ + k] = ck ? score : -INFINITY;
    }
}

// ---------------------------------------------------------------------------
// k3: argmax-select (first-max tie-break = jnp.argmax) or cs_ids; gather the
// selected span into slots [0, TK). grid = N*4 (16 tokens/block), block = 256.
// ---------------------------------------------------------------------------
__global__ __launch_bounds__(256) void k3_sel(
        const int* __restrict__ know, const int* __restrict__ ckm,
        const int* __restrict__ cs_ids, const int* __restrict__ use_flag,
        const float4* __restrict__ embed4, const float* __restrict__ ws_score,
        float4* __restrict__ out_enc4, float* __restrict__ out_mask) {
    const int n = blockIdx.x >> 2, c = blockIdx.x & 3;
    const int tid = threadIdx.x, w = tid >> 6, l = tid & 63;

    // uniform redundant argmax (32 cached reads; no divergence)
    int cs = 0;
    if (use_flag[0]) {
        cs = cs_ids[n];
    } else {
        float best = -INFINITY;
        #pragma unroll
        for (int j = 0; j < K_; ++j) {
            const float s = ws_score[n * K_ + j];
            if (s > best) { best = s; cs = j; }   // first-max tie-break
        }
    }
    const int ck = ckm[n * K_ + cs];

    __shared__ int toks[16];
    if (tid < 16) {
        const int tok = know[((size_t)n * K_ + cs) * TK_ + c * 16 + tid];
        toks[tid] = tok;
        out_mask[n * TF_ + c * 16 + tid] = (ck && tok) ? 1.f : 0.f;
    }
    __syncthreads();
    #pragma unroll
    for (int i = 0; i < 4; ++i) {                 // wave w: rows [4w, 4w+4)
        const int t = w * 4 + i;
        const int tok = toks[t];                  // wave-uniform -> scalar branch
        float4 v = {0.f, 0.f, 0.f, 0.f};
        if (ck && tok) v = embed4[(size_t)tok * D4_ + l];
        out_enc4[((size_t)n * TF_ + c * 16 + t) * D4_ + l] = v;
    }
}

// ---------------------------------------------------------------------------
extern "C" void kernel_launch(void* const* d_in, const int* in_sizes, int n_in,
                              void* d_out, int out_size, void* d_ws, size_t ws_size,
                              hipStream_t stream) {
    const int*   src      = (const int*)d_in[0];    // [N,TC]
    const int*   know     = (const int*)d_in[1];    // [N,K,TK]
    const int*   ckm      = (const int*)d_in[2];    // [N,K]
    const int*   cs_ids   = (const int*)d_in[3];    // [N]
    const int*   use_flag = (const int*)d_in[4];    // scalar
    const float* embed    = (const float*)d_in[5];  // [V,D]

    float* out      = (float*)d_out;
    float* out_mask = out + (size_t)N_ * TF_ * D_;  // [N,TF]
    float* out_attn = out_mask + N_ * TF_;          // [N,K]

    float*  ws       = (float*)d_ws;                // ~1.06 MB used
    float4* ws_part4 = (float4*)ws;
    int*    clen_p   = (int*)(ws + WS_CLENP);
    float*  ws_score = ws + WS_SCORE;

    hipLaunchKernelGGL(k1_ctx, dim3(N_ * 16), dim3(256), 0, stream,
                       src, (const float4*)embed, (float4*)out, out_mask,
                       ws_part4, clen_p);
    hipLaunchKernelGGL(k2_know, dim3(N_ * K_), dim3(256), 0, stream,
                       know, ckm, (const float4*)embed, ws_part4, clen_p,
                       out_attn, ws_score);
    hipLaunchKernelGGL(k3_sel, dim3(N_ * 4), dim3(256), 0, stream,
                       know, ckm, cs_ids, use_flag, (const float4*)embed,
                       ws_score, (float4*)out, out_mask);
}

// Round 15
// 109.641 us; speedup vs baseline: 1.3258x; 1.0469x over previous
//
#include <hip/hip_runtime.h>
#include <math.h>

// Problem constants
#define N_  64
#define TC_ 256
#define K_  32
#define TK_ 64
#define D_  256
#define D4_ 64            // float4 per embedding row
#define TF_ 320           // TK + TC
#define V_  32000

// ws layout (float offsets) — every slot written before read, no memset:
//   part   [1024][D]  f32  @ 0        per-(n,16-token-chunk) ctx partial sums
//   clen_p [1024]     int  @ 262144   per-chunk ctx token counts
//   score  [N][K]     f32  @ 263168   ck-masked scores (-inf pad) for argmax
#define WS_CLENP  262144
#define WS_SCORE  263168

__device__ __forceinline__ float4 fmask4(float4 v, int keep) {
    const float m = keep ? 1.f : 0.f;
    float4 r;
    r.x = m * v.x; r.y = m * v.y; r.z = m * v.z; r.w = m * v.w;
    return r;
}

// ---------------------------------------------------------------------------
// k1: ctx gather. grid = N*16 (16 tokens/block), block = 256 (4 waves).
// BRANCHLESS: always load the row (embed[0] is valid), mask afterwards ->
// the 4 row-loads per wave issue back-to-back (deep VMEM pipeline).
// ---------------------------------------------------------------------------
__global__ __launch_bounds__(256) void k1_ctx(
        const int* __restrict__ src, const float4* __restrict__ embed4,
        float4* __restrict__ out_enc4, float* __restrict__ out_mask,
        float4* __restrict__ ws_part4, int* __restrict__ clen_p) {
    const int b = blockIdx.x, n = b >> 4, c = b & 15;
    const int tid = threadIdx.x, w = tid >> 6, l = tid & 63;

    __shared__ int    toks[16];
    __shared__ float4 part[4][64];

    if (tid < 16) {
        const int tok = src[n * TC_ + c * 16 + tid];
        toks[tid] = tok;
        out_mask[n * TF_ + TK_ + c * 16 + tid] = tok ? 1.f : 0.f;
    }
    __syncthreads();

    float4 acc = {0.f, 0.f, 0.f, 0.f};
    #pragma unroll
    for (int i = 0; i < 4; ++i) {                 // wave w: tokens [4w, 4w+4)
        const int t = w * 4 + i;
        const int tok = toks[t];
        const float4 v = fmask4(embed4[(size_t)tok * D4_ + l], tok != 0);
        out_enc4[((size_t)n * TF_ + TK_ + c * 16 + t) * D4_ + l] = v;
        acc.x += v.x; acc.y += v.y; acc.z += v.z; acc.w += v.w;
    }
    part[w][l] = acc;
    __syncthreads();

    if (w == 0) {
        float4 a = part[0][l], b1 = part[1][l], p2 = part[2][l], p3 = part[3][l];
        a.x += b1.x + p2.x + p3.x;  a.y += b1.y + p2.y + p3.y;
        a.z += b1.z + p2.z + p3.z;  a.w += b1.w + p2.w + p3.w;
        ws_part4[(size_t)b * D4_ + l] = a;
        const unsigned long long ball = __ballot(l < 16 && toks[l] != 0);
        if (l == 0) clen_p[b] = __popcll(ball);
    }
}

// ---------------------------------------------------------------------------
// k2: knowledge scoring. grid = N*K = 2048 (one block per (n,k)), block = 256.
// 8 blocks/CU x 4 waves = 32 waves/CU. BRANCHLESS pooled gather: 16
// unconditional row-loads per wave, masked by fma-with-0.
// ctx staging spread across all 4 waves (4 chunk-partials each).
// ---------------------------------------------------------------------------
__global__ __launch_bounds__(256) void k2_know(
        const int* __restrict__ know, const int* __restrict__ ckm,
        const float4* __restrict__ embed4,
        const float4* __restrict__ ws_part4, const int* __restrict__ clen_p,
        float* __restrict__ out_attn, float* __restrict__ ws_score) {
    const int b = blockIdx.x, n = b >> 5, k = b & (K_ - 1);
    const int tid = threadIdx.x, w = tid >> 6, l = tid & 63;

    __shared__ int    ktoks[TK_];
    __shared__ float4 cpart[4][64];
    __shared__ float  redp[4];
    __shared__ int    lk_sh, lc_sh;

    if (tid < TK_) ktoks[tid] = know[((size_t)n * K_ + k) * TK_ + tid];
    {   // stage ctx sum: wave w sums chunks [4w, 4w+4)
        float4 s = {0.f, 0.f, 0.f, 0.f};
        #pragma unroll
        for (int c = 0; c < 4; ++c) {
            const float4 v = ws_part4[(size_t)(n * 16 + w * 4 + c) * D4_ + l];
            s.x += v.x; s.y += v.y; s.z += v.z; s.w += v.w;
        }
        cpart[w][l] = s;
    }
    if (w == 1) {                                 // reduce ctx length
        int cl = (l < 16) ? clen_p[n * 16 + l] : 0;
        #pragma unroll
        for (int o = 32; o > 0; o >>= 1) cl += __shfl_down(cl, o, 64);
        if (l == 0) lc_sh = cl;
    }
    __syncthreads();

    float4 acc = {0.f, 0.f, 0.f, 0.f};
    #pragma unroll
    for (int i = 0; i < 16; ++i) {                // wave w: rows [16w, 16w+16)
        const int tok = ktoks[w * 16 + i];
        const float4 v = embed4[(size_t)tok * D4_ + l];   // unconditional
        const float m = (tok != 0) ? 1.f : 0.f;
        acc.x = fmaf(m, v.x, acc.x); acc.y = fmaf(m, v.y, acc.y);
        acc.z = fmaf(m, v.z, acc.z); acc.w = fmaf(m, v.w, acc.w);
    }
    float4 cx = cpart[0][l];
    {
        const float4 c1 = cpart[1][l], c2 = cpart[2][l], c3 = cpart[3][l];
        cx.x += c1.x + c2.x + c3.x;  cx.y += c1.y + c2.y + c3.y;
        cx.z += c1.z + c2.z + c3.z;  cx.w += c1.w + c2.w + c3.w;
    }
    float p = acc.x * cx.x + acc.y * cx.y + acc.z * cx.z + acc.w * cx.w;
    #pragma unroll
    for (int o = 32; o > 0; o >>= 1) p += __shfl_down(p, o, 64);
    if (l == 0) redp[w] = p;
    if (w == 0) {
        const unsigned long long ball = __ballot(ktoks[l] != 0);
        if (l == 0) lk_sh = __popcll(ball);
    }
    __syncthreads();

    if (tid == 0) {
        const float dot = redp[0] + redp[1] + redp[2] + redp[3];
        const int ck = ckm[n * K_ + k];
        const int lc = max(lc_sh, 1);
        int lk = ck ? lk_sh : 0;  if (lk < 1) lk = 1;   // know_mask includes ck
        const float score =
            dot / (sqrtf((float)(D_ * lc)) * sqrtf((float)(D_ * lk)));
        out_attn[n * K_ + k] = ck ? score : 0.f;
        ws_score[n * K_ + k] = ck ? score : -INFINITY;
    }
}

// ---------------------------------------------------------------------------
// k3: argmax-select (first-max tie-break = jnp.argmax) or cs_ids; gather the
// selected span into slots [0, TK). grid = N*4 (16 tokens/block), block = 256.
// ---------------------------------------------------------------------------
__global__ __launch_bounds__(256) void k3_sel(
        const int* __restrict__ know, const int* __restrict__ ckm,
        const int* __restrict__ cs_ids, const int* __restrict__ use_flag,
        const float4* __restrict__ embed4, const float* __restrict__ ws_score,
        float4* __restrict__ out_enc4, float* __restrict__ out_mask) {
    const int n = blockIdx.x >> 2, c = blockIdx.x & 3;
    const int tid = threadIdx.x, w = tid >> 6, l = tid & 63;

    // uniform redundant argmax (32 cached reads; no divergence)
    int cs = 0;
    if (use_flag[0]) {
        cs = cs_ids[n];
    } else {
        float best = -INFINITY;
        #pragma unroll
        for (int j = 0; j < K_; ++j) {
            const float s = ws_score[n * K_ + j];
            if (s > best) { best = s; cs = j; }   // first-max tie-break
        }
    }
    const int ck = ckm[n * K_ + cs];

    __shared__ int toks[16];
    if (tid < 16) {
        const int tok = know[((size_t)n * K_ + cs) * TK_ + c * 16 + tid];
        toks[tid] = tok;
        out_mask[n * TF_ + c * 16 + tid] = (ck && tok) ? 1.f : 0.f;
    }
    __syncthreads();
    #pragma unroll
    for (int i = 0; i < 4; ++i) {                 // wave w: rows [4w, 4w+4)
        const int t = w * 4 + i;
        const int tok = toks[t];
        const float4 v =
            fmask4(embed4[(size_t)tok * D4_ + l], ck && tok != 0);
        out_enc4[((size_t)n * TF_ + c * 16 + t) * D4_ + l] = v;
    }
}

// ---------------------------------------------------------------------------
extern "C" void kernel_launch(void* const* d_in, const int* in_sizes, int n_in,
                              void* d_out, int out_size, void* d_ws, size_t ws_size,
                              hipStream_t stream) {
    const int*   src      = (const int*)d_in[0];    // [N,TC]
    const int*   know     = (const int*)d_in[1];    // [N,K,TK]
    const int*   ckm      = (const int*)d_in[2];    // [N,K]
    const int*   cs_ids   = (const int*)d_in[3];    // [N]
    const int*   use_flag = (const int*)d_in[4];    // scalar
    const float* embed    = (const float*)d_in[5];  // [V,D]

    float* out      = (float*)d_out;
    float* out_mask = out + (size_t)N_ * TF_ * D_;  // [N,TF]
    float* out_attn = out_mask + N_ * TF_;          // [N,K]

    float*  ws       = (float*)d_ws;                // ~1.06 MB used
    float4* ws_part4 = (float4*)ws;
    int*    clen_p   = (int*)(ws + WS_CLENP);
    float*  ws_score = ws + WS_SCORE;

    hipLaunchKernelGGL(k1_ctx, dim3(N_ * 16), dim3(256), 0, stream,
                       src, (const float4*)embed, (float4*)out, out_mask,
                       ws_part4, clen_p);
    hipLaunchKernelGGL(k2_know, dim3(N_ * K_), dim3(256), 0, stream,
                       know, ckm, (const float4*)embed, ws_part4, clen_p,
                       out_attn, ws_score);
    hipLaunchKernelGGL(k3_sel, dim3(N_ * 4), dim3(256), 0, stream,
                       know, ckm, cs_ids, use_flag, (const float4*)embed,
                       ws_score, (float4*)out, out_mask);
}